// Round 8
// baseline (205.353 us; speedup 1.0000x reference)
//
#include <hip/hip_runtime.h>
#include <math.h>

#define N_QUBITS 6
#define N_LAYERS 3
// table layout in d_ws: [0..17]=cos(rx/2), [18..35]=sin(rx/2), [36..50]=sigmoid(ent), [51]=pad

__global__ void prep_kernel(const float* __restrict__ rot,
                            const float* __restrict__ ent,
                            float* __restrict__ tbl) {
    const int t = threadIdx.x;
    if (t < 18) {
        const int l = t / 6, q = t % 6;
        float s_, c_;
        sincosf(rot[(l * 6 + q) * 3] * 0.5f, &s_, &c_);  // libm accuracy, runs once
        tbl[t] = c_;
        tbl[18 + t] = s_;
    } else if (t < 33) {
        const int u = t - 18;
        tbl[36 + u] = 1.0f / (1.0f + expf(-ent[u]));
    } else if (t == 33) {
        tbl[51] = 0.0f;
    }
}

// Each thread: 4 rows = 24 floats = 6 float4 in / 6 float4 out.
__global__ __launch_bounds__(256) void qc_main(
    const float* __restrict__ x,
    const float* __restrict__ tbl,
    float* __restrict__ out,
    int n_threads)
{
    const int idx = blockIdx.x * blockDim.x + threadIdx.x;
    if (idx >= n_threads) return;

    // Pull the 52-float constant table into SGPRs (wave-uniform).
    float cst[52];
    const float4* __restrict__ t4 = (const float4*)tbl;
#pragma unroll
    for (int i = 0; i < 13; ++i) {
        const float4 w = t4[i];
        cst[4 * i + 0] = __int_as_float(__builtin_amdgcn_readfirstlane(__float_as_int(w.x)));
        cst[4 * i + 1] = __int_as_float(__builtin_amdgcn_readfirstlane(__float_as_int(w.y)));
        cst[4 * i + 2] = __int_as_float(__builtin_amdgcn_readfirstlane(__float_as_int(w.z)));
        cst[4 * i + 3] = __int_as_float(__builtin_amdgcn_readfirstlane(__float_as_int(w.w)));
    }
#define CC(l, q) cst[(l) * 6 + (q)]
#define SS(l, q) cst[18 + (l) * 6 + (q)]
#define ST(l, j) cst[36 + (l) * 5 + (j)]

    const float4* __restrict__ xin = (const float4*)x + (size_t)idx * 6;
    float4 in[6];
#pragma unroll
    for (int i = 0; i < 6; ++i) in[i] = xin[i];   // issue all loads up front
    const float* vp = (const float*)in;

    float4* __restrict__ dst = (float4*)out + (size_t)idx * 6;
    float o12[12];

#pragma unroll
    for (int r = 0; r < 4; ++r) {
        float re[N_QUBITS], im[N_QUBITS];
#pragma unroll
        for (int q = 0; q < N_QUBITS; ++q) {
            // sin/cos(x*pi/2): x in [0,1) -> x/4 revolutions; HW sin/cos take revolutions.
            const float rev = vp[r * 6 + q] * 0.25f;
            im[q] = __builtin_amdgcn_sinf(rev);
            re[q] = __builtin_amdgcn_cosf(rev);
        }
#pragma unroll
        for (int l = 0; l < N_LAYERS; ++l) {
#pragma unroll
            for (int q = 0; q < N_QUBITS; ++q) {
                const float c_ = CC(l, q), s_ = SS(l, q);
                const float nr = c_ * re[q] + s_ * im[q];
                const float ni = c_ * im[q] - s_ * re[q];
                re[q] = nr;
                im[q] = ni;
            }
            float avg[N_QUBITS - 1];
#pragma unroll
            for (int j = 0; j < N_QUBITS - 1; ++j)
                avg[j] = (re[j] + re[j + 1]) * 0.5f;
            float nr_[N_QUBITS];
#pragma unroll
            for (int j = 0; j < N_QUBITS - 1; ++j) {
                const float st = ST(l, j);
                nr_[j] = (1.0f - st) * re[j] + st * avg[j];
            }
            {
                const float st = ST(l, N_QUBITS - 2);
                nr_[N_QUBITS - 1] =
                    (1.0f - st) * re[N_QUBITS - 1] + st * avg[N_QUBITS - 2];
            }
#pragma unroll
            for (int q = 0; q < N_QUBITS; ++q) re[q] = nr_[q];
        }
#pragma unroll
        for (int q = 0; q < N_QUBITS; ++q)
            o12[(r & 1) * 6 + q] =
                __builtin_amdgcn_sqrtf(re[q] * re[q] + im[q] * im[q]);

        if (r & 1) {  // flush every 2 rows (12 floats = 3 float4) to cap VGPR
            const int base = (r >> 1) * 3;
            dst[base + 0] = make_float4(o12[0], o12[1], o12[2], o12[3]);
            dst[base + 1] = make_float4(o12[4], o12[5], o12[6], o12[7]);
            dst[base + 2] = make_float4(o12[8], o12[9], o12[10], o12[11]);
        }
    }
#undef CC
#undef SS
#undef ST
}

extern "C" void kernel_launch(void* const* d_in, const int* in_sizes, int n_in,
                              void* d_out, int out_size, void* d_ws, size_t ws_size,
                              hipStream_t stream) {
    const float* x   = (const float*)d_in[0];
    const float* rot = (const float*)d_in[1];
    const float* ent = (const float*)d_in[2];
    float* out = (float*)d_out;
    float* tbl = (float*)d_ws;

    const int n_rows    = in_sizes[0] / N_QUBITS;   // 4194304
    const int n_threads = n_rows / 4;               // 1048576
    const int block = 256;
    const int grid = (n_threads + block - 1) / block;  // 4096

    prep_kernel<<<1, 64, 0, stream>>>(rot, ent, tbl);
    qc_main<<<grid, block, 0, stream>>>(x, tbl, out, n_threads);
}